// Round 1
// 742.811 us; speedup vs baseline: 1.0295x; 1.0295x over previous
//
#include <hip/hip_runtime.h>

#define NCOL  2048
#define NROW  64
#define NSTEP 1000
#define NTH   256
#define EPT   8   // columns per thread: 256*8 = 2048
#define NSEG  4   // temporal segments (blocks per row); NSEG=1 reverts to old layout
#define SEGLEN (NSTEP / NSEG)   // 250

typedef float vf4 __attribute__((ext_vector_type(4)));
typedef float vf2 __attribute__((ext_vector_type(2)));

// Grid = NROW * NSEG blocks. Block (row, seg) independently recomputes the
// row's evolution from u0 (register-resident state, no global traffic) for
// seg*SEGLEN warmup steps, then computes AND stores its SEGLEN-slab segment.
// Identical per-step arithmetic everywhere -> bitwise-identical trajectory.
//
// Key change vs previous version: __syncthreads() forced s_waitcnt vmcnt(0)
// before s_barrier, serializing every step on the ~900-cycle HBM write-ack
// of the previous step's trajectory stores (this WAS the 357ns/step).
// The barrier below waits lgkmcnt only -- trajectory stores are never read
// back, so they may stay in flight indefinitely.
__global__ __launch_bounds__(NTH) void ks_kernel(
    const float* __restrict__ u0,
    const float* __restrict__ c_in,
    const float* __restrict__ alpha_in,
    const float* __restrict__ beta_in,
    float* __restrict__ out)
{
    // Halo-pair exchange buffers: xch[phase][side][tid], side 0 = {u0,u1},
    // side 1 = {u6,u7}. Linear b64 accesses -> bank-conflict-free (replaces
    // the old strided vf2 full-row reads: 9.2M conflicts -> ~0).
    // Double-buffered on phase so ONE barrier per step is race-free.
    __shared__ vf2 xch[2][2][NTH];

    const int bid = blockIdx.x;
    const int row = bid & (NROW - 1);
    const int seg = bid >> 6;            // bid / NROW
    const int tid = threadIdx.x;

    const float c     = c_in[0];
    const float alpha = alpha_in[0];
    const float beta  = beta_in[0];

    const float dt     = 0.01f;
    const float inv2dx = 0.5f;   // 1/(2*dx), dx=1
    const float invdx2 = 1.0f;   // 1/dx^2
    const float invdx4 = 1.0f;   // 1/dx^4

    // ---- load u0 row into registers ----
    const float* __restrict__ urow = u0 + (size_t)row * NCOL;
    vf4 a = ((const vf4*)urow)[tid * 2 + 0];
    vf4 b = ((const vf4*)urow)[tid * 2 + 1];
    float u[EPT] = {a.x, a.y, a.z, a.w, b.x, b.y, b.z, b.w};

    if (seg == 0) {
        float* orow0 = out + (size_t)row * NCOL + tid * EPT;
        __builtin_nontemporal_store(a, (vf4*)orow0);
        __builtin_nontemporal_store(b, (vf4*)orow0 + 1);
    }

    int p = 0;
    auto step = [&]() {
        vf2 lo = {u[0], u[1]};
        vf2 hi = {u[6], u[7]};
        xch[p][0][tid] = lo;
        xch[p][1][tid] = hi;
        // LDS-only barrier: drain this wave's ds_writes, rendezvous. No vmcnt.
        asm volatile("s_waitcnt lgkmcnt(0)\n\ts_barrier" ::: "memory");
        // Periodic wrap falls out of the &255: tid 0 reads tid 255's {u6,u7}
        // = columns 2046,2047; tid 255 reads tid 0's {u0,u1} = columns 0,1.
        vf2 L = xch[p][1][(tid - 1) & (NTH - 1)];
        vf2 R = xch[p][0][(tid + 1) & (NTH - 1)];

        float w[12];
        w[0] = L.x; w[1] = L.y;
        #pragma unroll
        for (int i = 0; i < EPT; ++i) w[2 + i] = u[i];
        w[10] = R.x; w[11] = R.y;

        // Interior elements (2..5) first: they need no halo, so they overlap
        // the two ds_read_b64 latencies; edge elements after.
        constexpr int ord[EPT] = {2, 3, 4, 5, 0, 1, 6, 7};
        #pragma unroll
        for (int k = 0; k < EPT; ++k) {
            const int i = ord[k];
            float um2 = w[i];
            float um1 = w[i + 1];
            float uc  = w[i + 2];
            float up1 = w[i + 3];
            float up2 = w[i + 4];
            float u_x    = (up1 - um1) * inv2dx;
            float u_xx   = (up1 - 2.0f * uc + um1) * invdx2;
            float u_xxxx = (up2 - 4.0f * up1 + 6.0f * uc - 4.0f * um1 + um2) * invdx4;
            u[i] = uc + dt * (-c * uc * u_x - alpha * u_xx - beta * u_xxxx);
        }
        p ^= 1;
    };

    // ---- warmup: recompute state up to this segment's start (no stores) ----
    const int warm = seg * SEGLEN;
    for (int t = 0; t < warm; ++t) step();

    // ---- write phase: SEGLEN steps with trajectory stores ----
    const size_t slab = (size_t)NROW * NCOL;
    float* outp = out + (size_t)(warm + 1) * slab + (size_t)row * NCOL + tid * EPT;
    for (int t = 0; t < SEGLEN; ++t) {
        step();
        vf4 na = {u[0], u[1], u[2], u[3]};
        vf4 nb = {u[4], u[5], u[6], u[7]};
        __builtin_nontemporal_store(na, (vf4*)outp);
        __builtin_nontemporal_store(nb, (vf4*)outp + 1);
        outp += slab;
    }
    // no drain needed: dispatch-complete waits for outstanding stores
}

extern "C" void kernel_launch(void* const* d_in, const int* in_sizes, int n_in,
                              void* d_out, int out_size, void* d_ws, size_t ws_size,
                              hipStream_t stream) {
    const float* u0    = (const float*)d_in[0];
    const float* c     = (const float*)d_in[1];
    const float* alpha = (const float*)d_in[2];
    const float* beta  = (const float*)d_in[3];
    float* out = (float*)d_out;

    ks_kernel<<<NROW * NSEG, NTH, 0, stream>>>(u0, c, alpha, beta, out);
}

// Round 2
// 732.555 us; speedup vs baseline: 1.0439x; 1.0140x over previous
//
#include <hip/hip_runtime.h>

#define NCOL  2048
#define NROW  64
#define NSTEP 1000
#define NTH   256
#define EPT   8            // columns per thread
#define S     4            // sub-steps per halo exchange (temporal blocking)
#define HALO  (2*S)        // 8: stencil radius 2 per step
#define WIN   (EPT + 2*HALO)  // 24-float register window per thread
#define NSPLIT 4           // blocks per row; block g stores sub-step g+1 of each group

typedef float vf4 __attribute__((ext_vector_type(4)));

// One row is handled by NSPLIT blocks that ALL traverse all 1000 steps with
// identical arithmetic (bitwise-identical states); block g stores only steps
// t with (t-1)%4==g, so per-CU store rate is 2KB/step (under the ~24.6 GB/s
// per-CU ceiling that bound the previous version's write phase).
//
// Critical path = 1000 x per-step chain latency. Previous version paid the
// full LDS-roundtrip+barrier (~630 cyc) EVERY step (838 cyc/step measured).
// Here the halo exchange happens once per S=4 steps (radius-2 stencil ->
// 8-wide halo); each thread redundantly recomputes the shrinking halo region
// in registers. Valid window shrinks 24->20->16->12->8; the center 8 columns
// are valid at every intermediate sub-step, so per-step stores still work.
// Redundant recompute is bitwise-safe: same verbatim expression, same inputs.
// Model: 14 elems/step avg * 26 cyc + 630/4 ~ 522 cyc/step -> ~218 us.

#define DOSTEP(dst, src, LO, HI) do {                                         \
    _Pragma("unroll")                                                         \
    for (int k = (LO); k < (HI); ++k) {                                       \
        float um2 = (src)[k-2];                                               \
        float um1 = (src)[k-1];                                               \
        float uc  = (src)[k];                                                 \
        float up1 = (src)[k+1];                                               \
        float up2 = (src)[k+2];                                               \
        float u_x    = (up1 - um1) * inv2dx;                                  \
        float u_xx   = (up1 - 2.0f * uc + um1) * invdx2;                      \
        float u_xxxx = (up2 - 4.0f * up1 + 6.0f * uc - 4.0f * um1 + um2) * invdx4; \
        (dst)[k] = uc + dt * (-c * uc * u_x - alpha * u_xx - beta * u_xxxx);  \
    }                                                                         \
} while (0)

#define STORE8(arr) do {                                                      \
    vf4 sa = { (arr)[8],  (arr)[9],  (arr)[10], (arr)[11] };                  \
    vf4 sb = { (arr)[12], (arr)[13], (arr)[14], (arr)[15] };                  \
    __builtin_nontemporal_store(sa, (vf4*)outp);                              \
    __builtin_nontemporal_store(sb, (vf4*)outp + 1);                          \
} while (0)

__global__ __launch_bounds__(NTH, 1) void ks_kernel(
    const float* __restrict__ u0,
    const float* __restrict__ c_in,
    const float* __restrict__ alpha_in,
    const float* __restrict__ beta_in,
    float* __restrict__ out)
{
    // Halo-exchange buffer: full row image, double-buffered on group parity.
    // All LDS accesses are lane-contiguous b128 -> conflict-free.
    __shared__ float xbuf[2][NCOL];

    const int bid = blockIdx.x;
    const int row = bid & (NROW - 1);
    const int g   = bid >> 6;            // 0..3: which sub-step this block stores
    const int tid = threadIdx.x;
    const int base = tid * EPT;

    const float c     = c_in[0];
    const float alpha = alpha_in[0];
    const float beta  = beta_in[0];

    const float dt     = 0.01f;
    const float inv2dx = 0.5f;   // 1/(2*dx), dx=1
    const float invdx2 = 1.0f;   // 1/dx^2
    const float invdx4 = 1.0f;   // 1/dx^4

    // W/V index k corresponds to column (base - HALO + k) mod NCOL.
    // Own columns live at k = 8..15.
    float W[WIN], V[WIN];

    const float* __restrict__ urow = u0 + (size_t)row * NCOL;
    vf4 a  = ((const vf4*)urow)[tid * 2 + 0];
    vf4 b2 = ((const vf4*)urow)[tid * 2 + 1];
    W[8]  = a.x;  W[9]  = a.y;  W[10] = a.z;  W[11] = a.w;
    W[12] = b2.x; W[13] = b2.y; W[14] = b2.z; W[15] = b2.w;

    if (g == 0) {   // slab 0 = u0 copy
        float* orow0 = out + (size_t)row * NCOL + base;
        __builtin_nontemporal_store(a,  (vf4*)orow0);
        __builtin_nontemporal_store(b2, (vf4*)orow0 + 1);
    }

    const size_t slab = (size_t)NROW * NCOL;
    // This block stores slabs t = S*bq + (g+1).
    float* outp = out + (size_t)(g + 1) * slab + (size_t)row * NCOL + base;

    int p = 0;
    for (int bq = 0; bq < NSTEP / S; ++bq) {
        // ---- halo exchange: publish own 8 current columns, fetch 8+8 halo ----
        vf4 wa = { W[8],  W[9],  W[10], W[11] };
        vf4 wb = { W[12], W[13], W[14], W[15] };
        *(vf4*)&xbuf[p][base]     = wa;
        *(vf4*)&xbuf[p][base + 4] = wb;
        // LDS-only barrier: no vmcnt drain, trajectory stores stay in flight.
        asm volatile("s_waitcnt lgkmcnt(0)\n\ts_barrier" ::: "memory");
        vf4 l0 = *(const vf4*)&xbuf[p][(base - 8)  & (NCOL - 1)];
        vf4 l1 = *(const vf4*)&xbuf[p][(base - 4)  & (NCOL - 1)];
        vf4 r0 = *(const vf4*)&xbuf[p][(base + 8)  & (NCOL - 1)];
        vf4 r1 = *(const vf4*)&xbuf[p][(base + 12) & (NCOL - 1)];
        W[0]  = l0.x; W[1]  = l0.y; W[2]  = l0.z; W[3]  = l0.w;
        W[4]  = l1.x; W[5]  = l1.y; W[6]  = l1.z; W[7]  = l1.w;
        W[16] = r0.x; W[17] = r0.y; W[18] = r0.z; W[19] = r0.w;
        W[20] = r1.x; W[21] = r1.y; W[22] = r1.z; W[23] = r1.w;
        p ^= 1;
        // Double-buffer safety: reads of xbuf[p] at group bq are consumed
        // before this block's group-(bq+1) writes (which precede barrier bq+1);
        // xbuf[p] is rewritten only at bq+2, after barrier bq+1. No race.

        // ---- 4 sub-steps on the shrinking register window ----
        DOSTEP(V, W, 2, 22);            // t = S*bq + 1
        if (g == 0) STORE8(V);
        DOSTEP(W, V, 4, 20);            // t = S*bq + 2
        if (g == 1) STORE8(W);
        DOSTEP(V, W, 6, 18);            // t = S*bq + 3
        if (g == 2) STORE8(V);
        DOSTEP(W, V, 8, 16);            // t = S*bq + 4
        if (g == 3) STORE8(W);

        outp += (size_t)S * slab;
    }
    // no drain: dispatch-complete waits for outstanding nontemporal stores
}

extern "C" void kernel_launch(void* const* d_in, const int* in_sizes, int n_in,
                              void* d_out, int out_size, void* d_ws, size_t ws_size,
                              hipStream_t stream) {
    const float* u0    = (const float*)d_in[0];
    const float* c     = (const float*)d_in[1];
    const float* alpha = (const float*)d_in[2];
    const float* beta  = (const float*)d_in[3];
    float* out = (float*)d_out;

    ks_kernel<<<NROW * NSPLIT, NTH, 0, stream>>>(u0, c, alpha, beta, out);
}